// Round 8
// baseline (244.386 us; speedup 1.0000x reference)
//
#include <hip/hip_runtime.h>

// ModulatedConv2d (StyleGAN2): B=8, Cin=Cout=512, k=3, H=W=64.
//   s[b,c]     = style @ (mod_weight/sqrt(512))^T + bias          (fp32)
//   scale[b,o] = cs * rsqrt(cs^2 * sum_c wsq[o,c]*s^2 + eps)
//   out[b,o,p] = scale[b,o] * sum_{c,k} w[o,c,k] * (s[b,c]*x[b,c,p'])
// k_conv v8: v4 geometry (4 waves, wave = 64o x 8y x 32x, 16 acc frags,
// 0.33 reads/MFMA, 2x56KB dbuf) + v5 single-barrier phase loop + EXPLICIT
// in-wave pipelined fragment prefetch: reads of kx-block j+1 issue before
// MFMA cluster of block j (2 live frag sets, ping-pong), so LDS reads
// stream under MFMA via counted lgkmcnt. 1 wave/SIMD: 256 acc + 128 frag
// + ~60 addr VGPRs fits the 512-reg single-wave budget.

typedef __bf16 bf16x8 __attribute__((ext_vector_type(8)));
typedef float f32x16 __attribute__((ext_vector_type(16)));

#define AS1 __attribute__((address_space(1)))
#define AS3 __attribute__((address_space(3)))

__device__ __forceinline__ unsigned short f2bf(float f) {
  union { float f; unsigned int u; } v; v.f = f;
  unsigned int u = v.u;
  return (unsigned short)((u + 0x7fffu + ((u >> 16) & 1u)) >> 16);
}

__global__ void k_mod(const float* __restrict__ style, const float* __restrict__ mw,
                      const float* __restrict__ mb, float* __restrict__ s,
                      float* __restrict__ zp) {
  int t = blockIdx.x * 256 + threadIdx.x;   // 4096
  if (blockIdx.x == 0) {                    // 4KB zero page
    zp[threadIdx.x] = 0.f; zp[256 + threadIdx.x] = 0.f;
    zp[512 + threadIdx.x] = 0.f; zp[768 + threadIdx.x] = 0.f;
  }
  int b = t >> 9, c = t & 511;
  float acc = 0.f;
  for (int d = 0; d < 512; ++d) acc += style[b * 512 + d] * mw[c * 512 + d];
  s[t] = acc * 0.04419417382415922f + mb[c];  // 1/sqrt(512)
}

// One block per o: coalesced load of w[o,:,:] into LDS, then per-thread
// 2 c's: wsq + bf16 repack; all global writes coalesced (uint/float2).
__global__ __launch_bounds__(256) void k_wprep(
    const float* __restrict__ w, float* __restrict__ wsq,
    unsigned short* __restrict__ wbf) {
  __shared__ float wl[4608];
  int o = blockIdx.x;              // 512
  int t = threadIdx.x;             // 256
  const float* wp = w + (size_t)o * 4608;
  for (int i = t; i < 4608; i += 256) wl[i] = wp[i];
  __syncthreads();
  int c0 = t * 2;
  float q0 = 0.f, q1 = 0.f;
  unsigned int rr[9];
#pragma unroll
  for (int k = 0; k < 9; ++k) {
    float v0 = wl[c0 * 9 + k], v1 = wl[c0 * 9 + 9 + k];
    q0 += v0 * v0; q1 += v1 * v1;
    rr[k] = (unsigned int)f2bf(v0) | ((unsigned int)f2bf(v1) << 16);
  }
  *(float2*)&wsq[o * 512 + c0] = make_float2(q0, q1);
#pragma unroll
  for (int k = 0; k < 9; ++k)
    *(unsigned int*)&wbf[((size_t)k * 512 + o) * 512 + c0] = rr[k];
}

__global__ void k_scale(const float* __restrict__ wsq, const float* __restrict__ s,
                        float* __restrict__ scale) {
  int t = blockIdx.x * 256 + threadIdx.x;   // 4096
  int b = t >> 9, o = t & 511;
  float acc = 0.f;
  for (int c = 0; c < 512; ++c) {
    float sv = s[b * 512 + c];
    acc += wsq[o * 512 + c] * sv * sv;
  }
  const float cs = 0.014731391274719739f;   // 1/sqrt(4608)
  scale[t] = cs * rsqrtf(cs * cs * acc + 1e-8f);
}

// xt[b][y][x][c] = bf16(s[b,c] * x[b,c,y,x]).
// Coalesced float4 reads; 8x8 per-thread block -> LDS (XOR-swizzled 16B
// slots) -> 1KB-contiguous wave writes.
__global__ void k_xt(const float* __restrict__ x, const float* __restrict__ s,
                     unsigned short* __restrict__ xt) {
  __shared__ __align__(16) unsigned short tile[64 * 65 * 8];  // 66560 B
  int bid = blockIdx.x;            // 512 = b(8) * y(64)
  int b = bid >> 6, y = bid & 63;
  int t = threadIdx.x;             // 512
  int co = t >> 3, xo = t & 7;
  const float* xbase = x + ((size_t)(b * 512 + co * 8) * 64 + y) * 64 + xo * 8;
  float4 v[8][2];
#pragma unroll
  for (int j = 0; j < 8; ++j) {
    v[j][0] = *(const float4*)(xbase + (size_t)j * 4096);
    v[j][1] = *(const float4*)(xbase + (size_t)j * 4096 + 4);
  }
  float sv[8];
#pragma unroll
  for (int j = 0; j < 8; ++j) sv[j] = s[b * 512 + co * 8 + j];
#pragma unroll
  for (int k = 0; k < 8; ++k) {
    unsigned short r[8];
#pragma unroll
    for (int j = 0; j < 8; ++j) {
      float f = (k < 4) ? ((const float*)&v[j][0])[k & 3]
                        : ((const float*)&v[j][1])[k & 3];
      r[j] = f2bf(f * sv[j]);
    }
    int xr = xo * 8 + k;
    int unit = xr * 65 + (co ^ xr);
    *(ulonglong2*)&tile[unit * 8] = *(ulonglong2*)r;
  }
  __syncthreads();
  unsigned short* obase = xt + ((size_t)(b * 64 + y) * 64) * 512;
#pragma unroll
  for (int i = 0; i < 8; ++i) {
    int unit_o = i * 512 + t;
    int xr = unit_o >> 6, cor = unit_o & 63;
    int unit = xr * 65 + (cor ^ xr);
    *(ulonglong2*)&obase[(size_t)unit_o * 8] = *(const ulonglong2*)&tile[unit * 8];
  }
}

// ---------------- k_conv v8 ----------------
// Block = 128o x 16y x 32x, 4 waves: wid = wyy(0..1)*2 + wo(0..1).
// Wave = 64o x (8y x 32x), acc[oh in 0..1][ry in 0..7] = 16 f32x16 frags.
// Per 56KB buffer (56 issues x 1024B), entry = 16B = 8 c-values:
//   X: issues 0..19 : e = chunk(0..1)*612 + row(0..17)*34 + xi(0..33)
//      holds xt[yg*16+row-1][xg*32+xi-1][cc*16+chunk*8 ..+7]  (zp if OOB/pad)
//   W: issues 20..55: e2 = chunk*1152 + tap*128 + o(0..127)
//      holds wbf[tap][ob*128+o][cc*16+chunk*8 ..+7]
#define XISS 20
#define WOFF_US 10240    // 20 issues * 512 ushorts
#define BUFU    28672    // ushorts per buffer (57344 B)

__global__ __launch_bounds__(256, 1) void k_conv(
    const unsigned short* __restrict__ xt, const unsigned short* __restrict__ wbf,
    const float* __restrict__ scale, const float* __restrict__ zp,
    float* __restrict__ out) {
  __shared__ __align__(16) unsigned short lds[2 * BUFU];  // 114688 B

  int bid = blockIdx.x;            // 256 = 8 b * 4 ob * 4 yg * 2 xg
  int b = bid & 7;                 // XCD k owns batch b=k
  int rest = bid >> 3;
  int ob = rest & 3;
  int rest2 = rest >> 2;
  int yg = rest2 & 3;
  int xg = rest2 >> 2;

  int tid = threadIdx.x;
  int wid = tid >> 6;              // 0..3
  int wo = wid & 1, wyy = wid >> 1;
  int lane = tid & 63, ln31 = lane & 31, hi = lane >> 5;

  // ---- staging source pointers (14 issues per thread), advance 32B/phase ----
  const char* srcp[14];
  const char* xglob = (const char*)(xt + (size_t)b * 64 * 64 * 512);
#pragma unroll
  for (int i = 0; i < 14; ++i) {
    int is = wid + i * 4;          // 0..55
    const char* p;
    if (is < XISS) {
      int e = is * 64 + lane;
      int chunk = e / 612;
      int rem = e - chunk * 612;
      int row = rem / 34;
      int xi = rem - row * 34;
      int y = yg * 16 + row - 1, x = xg * 32 + xi - 1;
      bool ok = (chunk < 2) && (y >= 0) && (y < 64) && (x >= 0) && (x < 64);
      p = ok ? xglob + 2 * ((y * 64 + x) * 512 + chunk * 8) : (const char*)zp;
    } else {
      int e2 = (is - XISS) * 64 + lane;
      int chunk = e2 / 1152;
      int rem = e2 - chunk * 1152;
      int tap = rem >> 7, o = rem & 127;
      p = (const char*)wbf + 2 * ((tap * 512 + ob * 128 + o) * 512 + chunk * 8);
    }
    srcp[i] = p;
  }

  f32x16 acc[16];   // [oh*8 + ry]
#pragma unroll
  for (int i = 0; i < 16; ++i)
    acc[i] = (f32x16){0,0,0,0,0,0,0,0,0,0,0,0,0,0,0,0};

  auto STAGE = [&](int bufu) {
#pragma unroll
    for (int i = 0; i < 14; ++i) {
      __builtin_amdgcn_global_load_lds(
          (const AS1 void*)srcp[i],
          (AS3 void*)&lds[bufu + (wid + i * 4) * 512], 16, 0, 0);
      srcp[i] += 32;
    }
  };

  // Load one kx fragment set: 10 B-frags (rows) + 6 A-frags = 16 ds_read.
  auto LOADK = [&](const unsigned short* Xbp, const unsigned short* Abp,
                   int kx, bf16x8* bv, bf16x8* av) {
#pragma unroll
    for (int rr = 0; rr < 10; ++rr)
      bv[rr] = *(const bf16x8*)&Xbp[(rr * 34 + kx) * 8];
#pragma unroll
    for (int ky = 0; ky < 3; ++ky) {
      av[ky * 2]     = *(const bf16x8*)&Abp[(ky * 3 + kx) * 1024];
      av[ky * 2 + 1] = *(const bf16x8*)&Abp[(ky * 3 + kx) * 1024 + 256];
    }
  };

  // MFMA cluster for one kx set: 48 MFMA.
  auto MFK = [&](const bf16x8* bv, const bf16x8* av) {
    __builtin_amdgcn_s_setprio(1);
#pragma unroll
    for (int ky = 0; ky < 3; ++ky) {
#pragma unroll
      for (int ry = 0; ry < 8; ++ry) {
        acc[ry] = __builtin_amdgcn_mfma_f32_32x32x16_bf16(
            av[ky * 2], bv[ry + ky], acc[ry], 0, 0, 0);
        acc[8 + ry] = __builtin_amdgcn_mfma_f32_32x32x16_bf16(
            av[ky * 2 + 1], bv[ry + ky], acc[8 + ry], 0, 0, 0);
      }
    }
    __builtin_amdgcn_s_setprio(0);
  };

  // Pipelined phase: reads of block j+1 issue before MFMA of block j.
  auto COMPUTE = [&](const unsigned short* Xbp, const unsigned short* Abp) {
    bf16x8 b0[10], a0[6], b1[10], a1[6];
    LOADK(Xbp, Abp, 0, b0, a0);
    LOADK(Xbp, Abp, 1, b1, a1);
    MFK(b0, a0);                 // waits only b0/a0 (counted lgkm)
    LOADK(Xbp, Abp, 2, b0, a0);  // reuse set0 regs (WAR, in-order issue)
    MFK(b1, a1);
    MFK(b0, a0);
  };

  const unsigned short* Xb0 = &lds[(hi * 612 + wyy * 272 + ln31) * 8];
  const unsigned short* Ab0 = &lds[WOFF_US + (hi * 1152 + wo * 64 + ln31) * 8];
  const unsigned short* Xb1 = Xb0 + BUFU;
  const unsigned short* Ab1 = Ab0 + BUFU;

  STAGE(0);                                  // cc=0 -> buf0
  asm volatile("s_waitcnt vmcnt(0) lgkmcnt(0)" ::: "memory");
  __builtin_amdgcn_s_barrier();
  __builtin_amdgcn_sched_barrier(0);

#pragma unroll 1
  for (int t = 0; t < 16; ++t) {
    // phase A: stage buf1 (cc=2t+1), compute buf0 (cc=2t)
    STAGE(BUFU);
    COMPUTE(Xb0, Ab0);
    asm volatile("s_waitcnt vmcnt(0) lgkmcnt(0)" ::: "memory");
    __builtin_amdgcn_s_barrier();
    __builtin_amdgcn_sched_barrier(0);
    // phase B: stage buf0 (cc=2t+2), compute buf1 (cc=2t+1)
    if (t < 15) STAGE(0);
    COMPUTE(Xb1, Ab1);
    asm volatile("s_waitcnt vmcnt(0) lgkmcnt(0)" ::: "memory");
    __builtin_amdgcn_s_barrier();
    __builtin_amdgcn_sched_barrier(0);
  }

  // ---- epilogue: C/D layout col=lane&31, row=(reg&3)+8*(reg>>2)+4*(lane>>5) ----
  const float* scp = scale + b * 512 + ob * 128 + wo * 64;
  float* op = out + (((size_t)(b * 512 + ob * 128 + wo * 64) * 64) +
                     yg * 16 + wyy * 8) * 64 + xg * 32 + ln31;
#pragma unroll
  for (int oh = 0; oh < 2; ++oh) {
#pragma unroll
    for (int ry = 0; ry < 8; ++ry) {
      const f32x16& A = acc[oh * 8 + ry];
#pragma unroll
      for (int reg = 0; reg < 16; ++reg) {
        int orow = (reg & 3) + 8 * (reg >> 2) + hi * 4;
        int ol = oh * 32 + orow;
        op[(size_t)ol * 4096 + ry * 64] = A[reg] * scp[ol];
      }
    }
  }
}

extern "C" void kernel_launch(void* const* d_in, const int* in_sizes, int n_in,
                              void* d_out, int out_size, void* d_ws, size_t ws_size,
                              hipStream_t stream) {
  const float* x     = (const float*)d_in[0];  // [8,512,64,64]
  const float* style = (const float*)d_in[1];  // [8,512]
  const float* w     = (const float*)d_in[2];  // [1,512,512,3,3]
  const float* mw    = (const float*)d_in[3];  // [512,512]
  const float* mb    = (const float*)d_in[4];  // [512]
  float* out = (float*)d_out;

  char* ws = (char*)d_ws;
  float* zp    = (float*)ws;                       // 4 KB zeros
  float* s     = (float*)(ws + 4096);              // 16 KB
  float* scale = (float*)(ws + 20480);             // 16 KB
  float* wsq   = (float*)(ws + 36864);             // 1 MB
  unsigned short* wbf = (unsigned short*)(ws + 1085440);   // 4.72 MB [9][512][512]
  unsigned short* xt  = (unsigned short*)(ws + 5804032);   // 33.5 MB [8][64][64][512]

  k_mod  <<<16,   256, 0, stream>>>(style, mw, mb, s, zp);
  k_wprep<<<512,  256, 0, stream>>>(w, wsq, wbf);
  k_scale<<<16,   256, 0, stream>>>(wsq, s, scale);
  k_xt   <<<512,  512, 0, stream>>>(x, s, xt);
  k_conv <<<256,  256, 0, stream>>>(xt, wbf, scale, zp, out);
}

// Round 9
// 184.726 us; speedup vs baseline: 1.3230x; 1.3230x over previous
//
#include <hip/hip_runtime.h>

// ModulatedConv2d (StyleGAN2): B=8, Cin=Cout=512, k=3, H=W=64.
//   s[b,c]     = style @ (mod_weight/sqrt(512))^T + bias          (fp32)
//   scale[b,o] = cs * rsqrt(cs^2 * sum_c wsq[o,c]*s^2 + eps)
//   out[b,o,p] = scale[b,o] * sum_{c,k} w[o,c,k] * (s[b,c]*x[b,c,p'])
// k_conv v9 = v5 skeleton (8 waves = 2/SIMD, 2x56KB dbuf, fragment-entry
// conflict-free LDS, single drain+barrier per phase) + software wave-skew:
// SIMD s hosts waves {s, s+4}; class = (wid>>2)&1 gives each SIMD one wave
// in pattern L-M-L-M-L-M and one in L-L-M-L-M-M -> read bursts of one wave
// overlap MFMA clusters of the other. k_mod/k_scale: wave-dot rewrite.

typedef __bf16 bf16x8 __attribute__((ext_vector_type(8)));
typedef float f32x16 __attribute__((ext_vector_type(16)));

#define AS1 __attribute__((address_space(1)))
#define AS3 __attribute__((address_space(3)))
#define SB __builtin_amdgcn_sched_barrier(0)

__device__ __forceinline__ unsigned short f2bf(float f) {
  union { float f; unsigned int u; } v; v.f = f;
  unsigned int u = v.u;
  return (unsigned short)((u + 0x7fffu + ((u >> 16) & 1u)) >> 16);
}

__device__ __forceinline__ float dot8(float4 a0, float4 a1, float4 b0, float4 b1) {
  return a0.x*b0.x + a0.y*b0.y + a0.z*b0.z + a0.w*b0.w +
         a1.x*b1.x + a1.y*b1.y + a1.z*b1.z + a1.w*b1.w;
}

// s[b,c]: one wave per 4 outputs, lanes split d (coalesced 32B/lane).
__global__ __launch_bounds__(256) void k_mod(
    const float* __restrict__ style, const float* __restrict__ mw,
    const float* __restrict__ mb, float* __restrict__ s,
    float* __restrict__ zp) {
  if (blockIdx.x == 0) {                    // 4KB zero page
    zp[threadIdx.x] = 0.f; zp[256 + threadIdx.x] = 0.f;
    zp[512 + threadIdx.x] = 0.f; zp[768 + threadIdx.x] = 0.f;
  }
  int wv = blockIdx.x * 4 + (threadIdx.x >> 6);   // 0..1023
  int lane = threadIdx.x & 63;
  int t0 = wv * 4;
#pragma unroll
  for (int j = 0; j < 4; ++j) {
    int t = t0 + j, b = t >> 9, c = t & 511;
    const float4* mp = (const float4*)(mw + (size_t)c * 512 + lane * 8);
    const float4* sp = (const float4*)(style + (size_t)b * 512 + lane * 8);
    float p = dot8(mp[0], mp[1], sp[0], sp[1]);
#pragma unroll
    for (int off = 32; off; off >>= 1) p += __shfl_xor(p, off);
    if (lane == 0) s[t] = p * 0.04419417382415922f + mb[c];
  }
}

// One block per o: coalesced load of w[o,:,:] into LDS, then per-thread
// 2 c's: wsq + bf16 repack; coalesced uint/float2 writes.
__global__ __launch_bounds__(256) void k_wprep(
    const float* __restrict__ w, float* __restrict__ wsq,
    unsigned short* __restrict__ wbf) {
  __shared__ float wl[4608];
  int o = blockIdx.x;              // 512
  int t = threadIdx.x;             // 256
  const float* wp = w + (size_t)o * 4608;
  for (int i = t; i < 4608; i += 256) wl[i] = wp[i];
  __syncthreads();
  int c0 = t * 2;
  float q0 = 0.f, q1 = 0.f;
  unsigned int rr[9];
#pragma unroll
  for (int k = 0; k < 9; ++k) {
    float v0 = wl[c0 * 9 + k], v1 = wl[c0 * 9 + 9 + k];
    q0 += v0 * v0; q1 += v1 * v1;
    rr[k] = (unsigned int)f2bf(v0) | ((unsigned int)f2bf(v1) << 16);
  }
  *(float2*)&wsq[o * 512 + c0] = make_float2(q0, q1);
#pragma unroll
  for (int k = 0; k < 9; ++k)
    *(unsigned int*)&wbf[((size_t)k * 512 + o) * 512 + c0] = rr[k];
}

// scale[b,o]: one wave per o; wsq row read once (coalesced), 8 dots vs s^2.
__global__ __launch_bounds__(256) void k_scale(
    const float* __restrict__ wsq, const float* __restrict__ s,
    float* __restrict__ scale) {
  int o = blockIdx.x * 4 + (threadIdx.x >> 6);    // 128 blocks
  int lane = threadIdx.x & 63;
  const float4* wp = (const float4*)(wsq + (size_t)o * 512 + lane * 8);
  float4 w0 = wp[0], w1 = wp[1];
  const float cs = 0.014731391274719739f;   // 1/sqrt(4608)
#pragma unroll
  for (int b = 0; b < 8; ++b) {
    const float4* sp = (const float4*)(s + (size_t)b * 512 + lane * 8);
    float4 s0 = sp[0], s1 = sp[1];
    s0.x *= s0.x; s0.y *= s0.y; s0.z *= s0.z; s0.w *= s0.w;
    s1.x *= s1.x; s1.y *= s1.y; s1.z *= s1.z; s1.w *= s1.w;
    float p = dot8(w0, w1, s0, s1);
#pragma unroll
    for (int off = 32; off; off >>= 1) p += __shfl_xor(p, off);
    if (lane == 0) scale[b * 512 + o] = cs * rsqrtf(cs * cs * p + 1e-8f);
  }
}

// xt[b][y][x][c] = bf16(s[b,c] * x[b,c,y,x]).
// Coalesced float4 reads; 8x8 per-thread block -> LDS (XOR-swizzled 16B
// slots) -> 1KB-contiguous wave writes.
__global__ void k_xt(const float* __restrict__ x, const float* __restrict__ s,
                     unsigned short* __restrict__ xt) {
  __shared__ __align__(16) unsigned short tile[64 * 65 * 8];  // 66560 B
  int bid = blockIdx.x;            // 512 = b(8) * y(64)
  int b = bid >> 6, y = bid & 63;
  int t = threadIdx.x;             // 512
  int co = t >> 3, xo = t & 7;
  const float* xbase = x + ((size_t)(b * 512 + co * 8) * 64 + y) * 64 + xo * 8;
  float4 v[8][2];
#pragma unroll
  for (int j = 0; j < 8; ++j) {
    v[j][0] = *(const float4*)(xbase + (size_t)j * 4096);
    v[j][1] = *(const float4*)(xbase + (size_t)j * 4096 + 4);
  }
  float sv[8];
#pragma unroll
  for (int j = 0; j < 8; ++j) sv[j] = s[b * 512 + co * 8 + j];
#pragma unroll
  for (int k = 0; k < 8; ++k) {
    unsigned short r[8];
#pragma unroll
    for (int j = 0; j < 8; ++j) {
      float f = (k < 4) ? ((const float*)&v[j][0])[k & 3]
                        : ((const float*)&v[j][1])[k & 3];
      r[j] = f2bf(f * sv[j]);
    }
    int xr = xo * 8 + k;
    int unit = xr * 65 + (co ^ xr);
    *(ulonglong2*)&tile[unit * 8] = *(ulonglong2*)r;
  }
  __syncthreads();
  unsigned short* obase = xt + ((size_t)(b * 64 + y) * 64) * 512;
#pragma unroll
  for (int i = 0; i < 8; ++i) {
    int unit_o = i * 512 + t;
    int xr = unit_o >> 6, cor = unit_o & 63;
    int unit = xr * 65 + (cor ^ xr);
    *(ulonglong2*)&obase[(size_t)unit_o * 8] = *(const ulonglong2*)&tile[unit * 8];
  }
}

// ---------------- k_conv v9 ----------------
// Block = 128o x 16y x 32x, 8 waves: wid = wyy(0..3)*2 + wo(0..1).
// Wave = 64o x (4y x 32x), acc[oh in 0..1][ry in 0..3], 8 f32x16 frags.
// Per 56KB buffer (56 issues x 1024B), entry = 16B = 8 c-values:
//   X: issues 0..19 : e = chunk(0..1)*612 + row(0..17)*34 + xi(0..33)
//      holds xt[yg*16+row-1][xg*32+xi-1][cc*16+chunk*8 ..+7]  (zp if OOB/pad)
//   W: issues 20..55: e2 = chunk*1152 + tap*128 + o(0..127)
//      holds wbf[tap][ob*128+o][cc*16+chunk*8 ..+7]
#define XISS 20
#define WOFF_US 10240    // 20 issues * 512 ushorts
#define BUFU    28672    // ushorts per buffer (57344 B)

__global__ __launch_bounds__(512, 2) void k_conv(
    const unsigned short* __restrict__ xt, const unsigned short* __restrict__ wbf,
    const float* __restrict__ scale, const float* __restrict__ zp,
    float* __restrict__ out) {
  __shared__ __align__(16) unsigned short lds[2 * BUFU];  // 114688 B

  int bid = blockIdx.x;            // 256 = 8 b * 4 ob * 4 yg * 2 xg
  int b = bid & 7;                 // XCD k owns batch b=k
  int rest = bid >> 3;
  int ob = rest & 3;
  int rest2 = rest >> 2;
  int yg = rest2 & 3;
  int xg = rest2 >> 2;

  int tid = threadIdx.x;
  int wid = tid >> 6;              // 0..7
  int wo = wid & 1, wyy = wid >> 1;
  int lane = tid & 63, ln31 = lane & 31, hi = lane >> 5;
  int cls = (wid >> 2) & 1;        // SIMD s hosts waves {s, s+4}: one of each class

  // ---- staging source pointers (7 issues per thread), advance 32B/phase ----
  const char* srcp[7];
  const char* xglob = (const char*)(xt + (size_t)b * 64 * 64 * 512);
#pragma unroll
  for (int i = 0; i < 7; ++i) {
    int is = wid + i * 8;          // 0..55
    const char* p;
    if (is < XISS) {
      int e = is * 64 + lane;
      int chunk = e / 612;
      int rem = e - chunk * 612;
      int row = rem / 34;
      int xi = rem - row * 34;
      int y = yg * 16 + row - 1, x = xg * 32 + xi - 1;
      bool ok = (chunk < 2) && (y >= 0) && (y < 64) && (x >= 0) && (x < 64);
      p = ok ? xglob + 2 * ((y * 64 + x) * 512 + chunk * 8) : (const char*)zp;
    } else {
      int e2 = (is - XISS) * 64 + lane;
      int chunk = e2 / 1152;
      int rem = e2 - chunk * 1152;
      int tap = rem >> 7, o = rem & 127;
      p = (const char*)wbf + 2 * ((tap * 512 + ob * 128 + o) * 512 + chunk * 8);
    }
    srcp[i] = p;
  }

  f32x16 acc[8];   // [oh*4 + ry]
#pragma unroll
  for (int i = 0; i < 8; ++i)
    acc[i] = (f32x16){0,0,0,0,0,0,0,0,0,0,0,0,0,0,0,0};

  auto STAGE = [&](int bufu) {
#pragma unroll
    for (int i = 0; i < 7; ++i) {
      __builtin_amdgcn_global_load_lds(
          (const AS1 void*)srcp[i],
          (AS3 void*)&lds[bufu + (wid + i * 8) * 512], 16, 0, 0);
      srcp[i] += 32;
    }
  };

  // Load one kx fragment set: 6 B-frags (rows) + 6 A-frags = 12 ds_read.
  auto LOADK = [&](const unsigned short* Xbp, const unsigned short* Abp,
                   int kx, bf16x8* bv, bf16x8* av) {
#pragma unroll
    for (int rr = 0; rr < 6; ++rr)
      bv[rr] = *(const bf16x8*)&Xbp[(rr * 34 + kx) * 8];
#pragma unroll
    for (int ky = 0; ky < 3; ++ky) {
      av[ky * 2]     = *(const bf16x8*)&Abp[(ky * 3 + kx) * 1024];
      av[ky * 2 + 1] = *(const bf16x8*)&Abp[(ky * 3 + kx) * 1024 + 256];
    }
  };

  // MFMA cluster for one kx set: 24 MFMA.
  auto MFK = [&](const bf16x8* bv, const bf16x8* av) {
    __builtin_amdgcn_s_setprio(1);
#pragma unroll
    for (int ky = 0; ky < 3; ++ky) {
#pragma unroll
      for (int ry = 0; ry < 4; ++ry) {
        acc[ry] = __builtin_amdgcn_mfma_f32_32x32x16_bf16(
            av[ky * 2], bv[ry + ky], acc[ry], 0, 0, 0);
        acc[4 + ry] = __builtin_amdgcn_mfma_f32_32x32x16_bf16(
            av[ky * 2 + 1], bv[ry + ky], acc[4 + ry], 0, 0, 0);
      }
    }
    __builtin_amdgcn_s_setprio(0);
  };

  // Skewed compute: class 0 = L M L M L M, class 1 = L L M L M M.
  auto COMPUTE = [&](const unsigned short* Xbp, const unsigned short* Abp) {
    bf16x8 b0[6], a0[6], b1[6], a1[6];
    if (cls == 0) {
      LOADK(Xbp, Abp, 0, b0, a0); SB;
      MFK(b0, a0); SB;
      LOADK(Xbp, Abp, 1, b1, a1); SB;
      MFK(b1, a1); SB;
      LOADK(Xbp, Abp, 2, b0, a0); SB;
      MFK(b0, a0);
    } else {
      LOADK(Xbp, Abp, 0, b0, a0);
      LOADK(Xbp, Abp, 1, b1, a1); SB;
      MFK(b0, a0); SB;
      LOADK(Xbp, Abp, 2, b0, a0); SB;
      MFK(b1, a1); SB;
      MFK(b0, a0);
    }
  };

  const unsigned short* Xb0 = &lds[(hi * 612 + wyy * 4 * 34 + ln31) * 8];
  const unsigned short* Ab0 = &lds[WOFF_US + (hi * 1152 + wo * 64 + ln31) * 8];
  const unsigned short* Xb1 = Xb0 + BUFU;
  const unsigned short* Ab1 = Ab0 + BUFU;

  STAGE(0);                                  // cc=0 -> buf0
  asm volatile("s_waitcnt vmcnt(0) lgkmcnt(0)" ::: "memory");
  __builtin_amdgcn_s_barrier();
  SB;

#pragma unroll 1
  for (int t = 0; t < 16; ++t) {
    // phase A: stage buf1 (cc=2t+1), compute buf0 (cc=2t)
    STAGE(BUFU);
    COMPUTE(Xb0, Ab0);
    asm volatile("s_waitcnt vmcnt(0) lgkmcnt(0)" ::: "memory");
    __builtin_amdgcn_s_barrier();
    SB;
    // phase B: stage buf0 (cc=2t+2), compute buf1 (cc=2t+1)
    if (t < 15) STAGE(0);
    COMPUTE(Xb1, Ab1);
    asm volatile("s_waitcnt vmcnt(0) lgkmcnt(0)" ::: "memory");
    __builtin_amdgcn_s_barrier();
    SB;
  }

  // ---- epilogue: C/D layout col=lane&31, row=(reg&3)+8*(reg>>2)+4*(lane>>5) ----
  const float* scp = scale + b * 512 + ob * 128 + wo * 64;
  float* op = out + (((size_t)(b * 512 + ob * 128 + wo * 64) * 64) +
                     yg * 16 + wyy * 4) * 64 + xg * 32 + ln31;
#pragma unroll
  for (int oh = 0; oh < 2; ++oh) {
#pragma unroll
    for (int ry = 0; ry < 4; ++ry) {
      const f32x16& A = acc[oh * 4 + ry];
#pragma unroll
      for (int reg = 0; reg < 16; ++reg) {
        int orow = (reg & 3) + 8 * (reg >> 2) + hi * 4;
        int ol = oh * 32 + orow;
        op[(size_t)ol * 4096 + ry * 64] = A[reg] * scp[ol];
      }
    }
  }
}

extern "C" void kernel_launch(void* const* d_in, const int* in_sizes, int n_in,
                              void* d_out, int out_size, void* d_ws, size_t ws_size,
                              hipStream_t stream) {
  const float* x     = (const float*)d_in[0];  // [8,512,64,64]
  const float* style = (const float*)d_in[1];  // [8,512]
  const float* w     = (const float*)d_in[2];  // [1,512,512,3,3]
  const float* mw    = (const float*)d_in[3];  // [512,512]
  const float* mb    = (const float*)d_in[4];  // [512]
  float* out = (float*)d_out;

  char* ws = (char*)d_ws;
  float* zp    = (float*)ws;                       // 4 KB zeros
  float* s     = (float*)(ws + 4096);              // 16 KB
  float* scale = (float*)(ws + 20480);             // 16 KB
  float* wsq   = (float*)(ws + 36864);             // 1 MB
  unsigned short* wbf = (unsigned short*)(ws + 1085440);   // 4.72 MB [9][512][512]
  unsigned short* xt  = (unsigned short*)(ws + 5804032);   // 33.5 MB [8][64][64][512]

  k_mod  <<<256,  256, 0, stream>>>(style, mw, mb, s, zp);
  k_wprep<<<512,  256, 0, stream>>>(w, wsq, wbf);
  k_scale<<<128,  256, 0, stream>>>(wsq, s, scale);
  k_xt   <<<512,  512, 0, stream>>>(x, s, xt);
  k_conv <<<256,  512, 0, stream>>>(xt, wbf, scale, zp, out);
}

// Round 10
// 177.961 us; speedup vs baseline: 1.3733x; 1.0380x over previous
//
#include <hip/hip_runtime.h>

// ModulatedConv2d (StyleGAN2): B=8, Cin=Cout=512, k=3, H=W=64.
//   s[b,c]     = style @ (mod_weight/sqrt(512))^T + bias          (fp32)
//   scale[b,o] = cs * rsqrt(cs^2 * sum_c wsq[o,c]*s^2 + eps)
//   out[b,o,p] = scale[b,o] * sum_{c,k} w[o,c,k] * (s[b,c]*x[b,c,p'])
// k_conv v10: W direct L2->register (coalesced 2KB gathers from
// wbf2[tap][cc][o][16c], double-buffered A-prefetch) + quad-buffered
// X-only LDS (4x24KB) staged 2 phases ahead with counted vmcnt(9) and a
// SINGLE barrier per phase. No vmcnt(0) drain anywhere in the main loop.

typedef __bf16 bf16x8 __attribute__((ext_vector_type(8)));
typedef float f32x16 __attribute__((ext_vector_type(16)));

#define AS1 __attribute__((address_space(1)))
#define AS3 __attribute__((address_space(3)))
#define SB __builtin_amdgcn_sched_barrier(0)

__device__ __forceinline__ unsigned short f2bf(float f) {
  union { float f; unsigned int u; } v; v.f = f;
  unsigned int u = v.u;
  return (unsigned short)((u + 0x7fffu + ((u >> 16) & 1u)) >> 16);
}

__device__ __forceinline__ float dot8(float4 a0, float4 a1, float4 b0, float4 b1) {
  return a0.x*b0.x + a0.y*b0.y + a0.z*b0.z + a0.w*b0.w +
         a1.x*b1.x + a1.y*b1.y + a1.z*b1.z + a1.w*b1.w;
}

// s[b,c]: one wave per 4 outputs, lanes split d (coalesced 32B/lane).
__global__ __launch_bounds__(256) void k_mod(
    const float* __restrict__ style, const float* __restrict__ mw,
    const float* __restrict__ mb, float* __restrict__ s,
    float* __restrict__ zp) {
  if (blockIdx.x == 0) {                    // 4KB zero page
    zp[threadIdx.x] = 0.f; zp[256 + threadIdx.x] = 0.f;
    zp[512 + threadIdx.x] = 0.f; zp[768 + threadIdx.x] = 0.f;
  }
  int wv = blockIdx.x * 4 + (threadIdx.x >> 6);   // 0..1023
  int lane = threadIdx.x & 63;
  int t0 = wv * 4;
#pragma unroll
  for (int j = 0; j < 4; ++j) {
    int t = t0 + j, b = t >> 9, c = t & 511;
    const float4* mp = (const float4*)(mw + (size_t)c * 512 + lane * 8);
    const float4* sp = (const float4*)(style + (size_t)b * 512 + lane * 8);
    float p = dot8(mp[0], mp[1], sp[0], sp[1]);
#pragma unroll
    for (int off = 32; off; off >>= 1) p += __shfl_xor(p, off);
    if (lane == 0) s[t] = p * 0.04419417382415922f + mb[c];
  }
}

// wbf2[tap][cc(32)][o(512)][16c] bf16 + wsq[o][c]; per thread 2 c's.
__global__ __launch_bounds__(256) void k_wprep(
    const float* __restrict__ w, float* __restrict__ wsq,
    unsigned short* __restrict__ wbf2) {
  __shared__ float wl[4608];
  int o = blockIdx.x;              // 512
  int t = threadIdx.x;             // 256
  const float* wp = w + (size_t)o * 4608;
  for (int i = t; i < 4608; i += 256) wl[i] = wp[i];
  __syncthreads();
  int c0 = t * 2;
  float q0 = 0.f, q1 = 0.f;
  unsigned int rr[9];
#pragma unroll
  for (int k = 0; k < 9; ++k) {
    float v0 = wl[c0 * 9 + k], v1 = wl[c0 * 9 + 9 + k];
    q0 += v0 * v0; q1 += v1 * v1;
    rr[k] = (unsigned int)f2bf(v0) | ((unsigned int)f2bf(v1) << 16);
  }
  *(float2*)&wsq[o * 512 + c0] = make_float2(q0, q1);
#pragma unroll
  for (int k = 0; k < 9; ++k) {
    size_t idx = ((size_t)(k * 32 + (c0 >> 4)) * 512 + o) * 16 +
                 ((c0 >> 3) & 1) * 8 + (c0 & 7);
    *(unsigned int*)&wbf2[idx] = rr[k];
  }
}

// scale[b,o]: one wave per o; wsq row read once (coalesced), 8 dots vs s^2.
__global__ __launch_bounds__(256) void k_scale(
    const float* __restrict__ wsq, const float* __restrict__ s,
    float* __restrict__ scale) {
  int o = blockIdx.x * 4 + (threadIdx.x >> 6);    // 128 blocks
  int lane = threadIdx.x & 63;
  const float4* wp = (const float4*)(wsq + (size_t)o * 512 + lane * 8);
  float4 w0 = wp[0], w1 = wp[1];
  const float cs = 0.014731391274719739f;   // 1/sqrt(4608)
#pragma unroll
  for (int b = 0; b < 8; ++b) {
    const float4* sp = (const float4*)(s + (size_t)b * 512 + lane * 8);
    float4 s0 = sp[0], s1 = sp[1];
    s0.x *= s0.x; s0.y *= s0.y; s0.z *= s0.z; s0.w *= s0.w;
    s1.x *= s1.x; s1.y *= s1.y; s1.z *= s1.z; s1.w *= s1.w;
    float p = dot8(w0, w1, s0, s1);
#pragma unroll
    for (int off = 32; off; off >>= 1) p += __shfl_xor(p, off);
    if (lane == 0) scale[b * 512 + o] = cs * rsqrtf(cs * cs * p + 1e-8f);
  }
}

// xt[b][y][x][c] = bf16(s[b,c] * x[b,c,y,x]).
__global__ void k_xt(const float* __restrict__ x, const float* __restrict__ s,
                     unsigned short* __restrict__ xt) {
  __shared__ __align__(16) unsigned short tile[64 * 65 * 8];  // 66560 B
  int bid = blockIdx.x;            // 512 = b(8) * y(64)
  int b = bid >> 6, y = bid & 63;
  int t = threadIdx.x;             // 512
  int co = t >> 3, xo = t & 7;
  const float* xbase = x + ((size_t)(b * 512 + co * 8) * 64 + y) * 64 + xo * 8;
  float4 v[8][2];
#pragma unroll
  for (int j = 0; j < 8; ++j) {
    v[j][0] = *(const float4*)(xbase + (size_t)j * 4096);
    v[j][1] = *(const float4*)(xbase + (size_t)j * 4096 + 4);
  }
  float sv[8];
#pragma unroll
  for (int j = 0; j < 8; ++j) sv[j] = s[b * 512 + co * 8 + j];
#pragma unroll
  for (int k = 0; k < 8; ++k) {
    unsigned short r[8];
#pragma unroll
    for (int j = 0; j < 8; ++j) {
      float f = (k < 4) ? ((const float*)&v[j][0])[k & 3]
                        : ((const float*)&v[j][1])[k & 3];
      r[j] = f2bf(f * sv[j]);
    }
    int xr = xo * 8 + k;
    int unit = xr * 65 + (co ^ xr);
    *(ulonglong2*)&tile[unit * 8] = *(ulonglong2*)r;
  }
  __syncthreads();
  unsigned short* obase = xt + ((size_t)(b * 64 + y) * 64) * 512;
#pragma unroll
  for (int i = 0; i < 8; ++i) {
    int unit_o = i * 512 + t;
    int xr = unit_o >> 6, cor = unit_o & 63;
    int unit = xr * 65 + (cor ^ xr);
    *(ulonglong2*)&obase[(size_t)unit_o * 8] = *(const ulonglong2*)&tile[unit * 8];
  }
}

// ---------------- k_conv v10 ----------------
// Block = 128o x 16y x 32x, 8 waves: wid = wyy(0..3)*2 + wo(0..1).
// Wave = 64o x (4y x 32x), acc = 8 f32x16 frags.
// X-only LDS, quad-buffered: buffer = 24 issues x 1024B (20 real + 4 pad).
//   entry e = chunk(0..1)*612 + row(0..17)*34 + xi(0..33):
//   holds xt[yg*16+row-1][xg*32+xi-1][cc*16+chunk*8 ..+7]  (zp if OOB/pad)
// W: direct global->reg from wbf2[tap][cc][o][16c]; one A-frag = one
// coalesced 2KB dwordx4 gather; A double-buffered (prefetch next kx).
#define XISS 20
#define BUFU  12288      // ushorts per buffer (24576 B)

__global__ __launch_bounds__(512, 2) void k_conv(
    const unsigned short* __restrict__ xt, const unsigned short* __restrict__ wbf2,
    const float* __restrict__ scale, const float* __restrict__ zp,
    float* __restrict__ out) {
  __shared__ __align__(16) unsigned short lds[4 * BUFU];  // 98304 B

  int bid = blockIdx.x;            // 256 = 8 b * 4 ob * 4 yg * 2 xg
  int b = bid & 7;                 // XCD k owns batch b=k
  int rest = bid >> 3;
  int ob = rest & 3;
  int rest2 = rest >> 2;
  int yg = rest2 & 3;
  int xg = rest2 >> 2;

  int tid = threadIdx.x;
  int wid = tid >> 6;              // 0..7
  int wo = wid & 1, wyy = wid >> 1;
  int lane = tid & 63, ln31 = lane & 31, hi = lane >> 5;

  // ---- X staging source pointers (3 issues per thread), +32B/phase ----
  const char* srcp[3];
  const char* xglob = (const char*)(xt + (size_t)b * 64 * 64 * 512);
#pragma unroll
  for (int i = 0; i < 3; ++i) {
    int is = wid + i * 8;          // 0..23
    const char* p = (const char*)zp;
    if (is < XISS) {
      int e = is * 64 + lane;
      int chunk = e / 612;
      int rem = e - chunk * 612;
      int row = rem / 34;
      int xi = rem - row * 34;
      int y = yg * 16 + row - 1, x = xg * 32 + xi - 1;
      bool ok = (chunk < 2) && (y >= 0) && (y < 64) && (x >= 0) && (x < 64);
      if (ok) p = xglob + 2 * ((y * 64 + x) * 512 + chunk * 8);
    }
    srcp[i] = p;
  }

  // ---- A (weight) lane base pointers: wbf2[tap][cc][o][16c] ----
  // lane reads 16B at o = ob*128 + wo*64 + oh*32 + ln31, c-half = hi.
  const char* aw0 = (const char*)wbf2 +
      2 * (((size_t)(ob * 128 + wo * 64 + ln31)) * 16 + hi * 8);
  const char* aw1 = aw0 + 1024;    // +32 o's

  f32x16 acc[8];   // [oh*4 + ry]
#pragma unroll
  for (int i = 0; i < 8; ++i)
    acc[i] = (f32x16){0,0,0,0,0,0,0,0,0,0,0,0,0,0,0,0};

  auto STAGE = [&](int bufu, bool real) {
#pragma unroll
    for (int i = 0; i < 3; ++i) {
      const char* src = real ? srcp[i] : (const char*)zp;
      __builtin_amdgcn_global_load_lds(
          (const AS1 void*)src,
          (AS3 void*)&lds[bufu + (wid + i * 8) * 512], 16, 0, 0);
      srcp[i] += 32;
    }
  };

  // A-frags for one kx: 6 coalesced 2KB gathers (tap stride 512KB, cc 16KB).
  auto LOADA = [&](int kx, int aoff, bf16x8* A) {
#pragma unroll
    for (int ky = 0; ky < 3; ++ky) {
      int tap = ky * 3 + kx;
      A[ky * 2]     = *(const bf16x8*)(aw0 + (size_t)tap * 524288 + aoff);
      A[ky * 2 + 1] = *(const bf16x8*)(aw1 + (size_t)tap * 524288 + aoff);
    }
  };

  auto LOADB = [&](const unsigned short* Xbp, int kx, bf16x8* bv) {
#pragma unroll
    for (int rr = 0; rr < 6; ++rr)
      bv[rr] = *(const bf16x8*)&Xbp[(rr * 34 + kx) * 8];
  };

  auto MFK = [&](const bf16x8* av, const bf16x8* bv) {
    __builtin_amdgcn_s_setprio(1);
#pragma unroll
    for (int ky = 0; ky < 3; ++ky) {
#pragma unroll
      for (int ry = 0; ry < 4; ++ry) {
        acc[ry] = __builtin_amdgcn_mfma_f32_32x32x16_bf16(
            av[ky * 2], bv[ry + ky], acc[ry], 0, 0, 0);
        acc[4 + ry] = __builtin_amdgcn_mfma_f32_32x32x16_bf16(
            av[ky * 2 + 1], bv[ry + ky], acc[4 + ry], 0, 0, 0);
      }
    }
    __builtin_amdgcn_s_setprio(0);
  };

  // One cc-phase. Su = A set entering (kx0 data), Sl = other set.
  // vmcnt(9) leaves this phase's 3 X-DMA + 6 A-prefetch in flight; waits
  // only the previous phase's X-DMA (issued ~1 phase ago -> free).
  auto PHASE = [&](const unsigned short* Xbp, int stageBufU, bool real,
                   bf16x8* Su, bf16x8* Sl, int aoff) {
    bf16x8 bv[6];
    // kx0
    LOADB(Xbp, 0, bv);
    STAGE(stageBufU, real);
    LOADA(1, aoff, Sl);
    MFK(Su, bv);
    // kx1
    LOADB(Xbp, 1, bv);
    LOADA(2, aoff, Su);
    MFK(Sl, bv);
    // kx2
    LOADB(Xbp, 2, bv);
    LOADA(0, aoff + 16384, Sl);   // next phase's kx0
    MFK(Su, bv);
    asm volatile("s_waitcnt vmcnt(9)" ::: "memory");
    __builtin_amdgcn_s_barrier();
    SB;
  };

  const unsigned short* Xw = &lds[(hi * 612 + wyy * 136 + ln31) * 8];
  const unsigned short* Xq0 = Xw;
  const unsigned short* Xq1 = Xw + BUFU;
  const unsigned short* Xq2 = Xw + 2 * BUFU;
  const unsigned short* Xq3 = Xw + 3 * BUFU;

  bf16x8 SA[6], SB_[6];

  STAGE(0, true);                   // cc0 -> buf0
  STAGE(BUFU, true);                // cc1 -> buf1
  LOADA(0, 0, SA);                  // A(kx0, cc0)
  asm volatile("s_waitcnt vmcnt(9)" ::: "memory");   // wait buf0 only
  __builtin_amdgcn_s_barrier();
  SB;

  int aoff = 0;
#pragma unroll 1
  for (int t4 = 0; t4 < 8; ++t4) {
    bool r = (t4 < 7);
    PHASE(Xq0, 2 * BUFU, true, SA, SB_, aoff); aoff += 16384;
    PHASE(Xq1, 3 * BUFU, true, SB_, SA, aoff); aoff += 16384;
    PHASE(Xq2, 0,        r,    SA, SB_, aoff); aoff += 16384;
    PHASE(Xq3, 1 * BUFU, r,    SB_, SA, aoff); aoff += 16384;
  }

  // ---- epilogue: C/D layout col=lane&31, row=(reg&3)+8*(reg>>2)+4*(lane>>5) ----
  const float* scp = scale + b * 512 + ob * 128 + wo * 64;
  float* op = out + (((size_t)(b * 512 + ob * 128 + wo * 64) * 64) +
                     yg * 16 + wyy * 4) * 64 + xg * 32 + ln31;
#pragma unroll
  for (int oh = 0; oh < 2; ++oh) {
#pragma unroll
    for (int ry = 0; ry < 4; ++ry) {
      const f32x16& A = acc[oh * 4 + ry];
#pragma unroll
      for (int reg = 0; reg < 16; ++reg) {
        int orow = (reg & 3) + 8 * (reg >> 2) + hi * 4;
        int ol = oh * 32 + orow;
        op[(size_t)ol * 4096 + ry * 64] = A[reg] * scp[ol];
      }
    }
  }
}

extern "C" void kernel_launch(void* const* d_in, const int* in_sizes, int n_in,
                              void* d_out, int out_size, void* d_ws, size_t ws_size,
                              hipStream_t stream) {
  const float* x     = (const float*)d_in[0];  // [8,512,64,64]
  const float* style = (const float*)d_in[1];  // [8,512]
  const float* w     = (const float*)d_in[2];  // [1,512,512,3,3]
  const float* mw    = (const float*)d_in[3];  // [512,512]
  const float* mb    = (const float*)d_in[4];  // [512]
  float* out = (float*)d_out;

  char* ws = (char*)d_ws;
  float* zp    = (float*)ws;                       // 4 KB zeros
  float* s     = (float*)(ws + 4096);              // 16 KB
  float* scale = (float*)(ws + 20480);             // 16 KB
  float* wsq   = (float*)(ws + 36864);             // 1 MB
  unsigned short* wbf2 = (unsigned short*)(ws + 1085440);  // 4.72 MB [9][32][512][16]
  unsigned short* xt   = (unsigned short*)(ws + 5804032);  // 33.5 MB [8][64][64][512]

  k_mod  <<<256,  256, 0, stream>>>(style, mw, mb, s, zp);
  k_wprep<<<512,  256, 0, stream>>>(w, wsq, wbf2);
  k_scale<<<128,  256, 0, stream>>>(wsq, s, scale);
  k_xt   <<<512,  512, 0, stream>>>(x, s, xt);
  k_conv <<<256,  512, 0, stream>>>(xt, wbf2, scale, zp, out);
}

// Round 11
// 175.538 us; speedup vs baseline: 1.3922x; 1.0138x over previous
//
#include <hip/hip_runtime.h>

// ModulatedConv2d (StyleGAN2): B=8, Cin=Cout=512, k=3, H=W=64.
//   s[b,c]     = style @ (mod_weight/sqrt(512))^T + bias          (fp32)
//   scale[b,o] = cs * rsqrt(cs^2 * sum_c wsq[o,c]*s^2 + eps)
//   out[b,o,p] = scale[b,o] * sum_{c,k} w[o,c,k] * (s[b,c]*x[b,c,p'])
// k_conv v11 = v10 (8 waves = 2/SIMD, W direct L2->reg ping-pong, X-only
// LDS, fragment-entry conflict-free layout, single barrier per phase) with
// BK=32: each phase covers TWO 16-c subchunks -> 16 phases x 144 MFMA/wave
// (6 MFK clusters), amortizing the ~7k-cyc fixed per-phase overhead 2x.
// X buffer = [chunk0..3][row 0..17][xi 0..33] 16B entries, 2 x 40KB dbuf.

typedef __bf16 bf16x8 __attribute__((ext_vector_type(8)));
typedef float f32x16 __attribute__((ext_vector_type(16)));

#define AS1 __attribute__((address_space(1)))
#define AS3 __attribute__((address_space(3)))
#define SB __builtin_amdgcn_sched_barrier(0)

__device__ __forceinline__ unsigned short f2bf(float f) {
  union { float f; unsigned int u; } v; v.f = f;
  unsigned int u = v.u;
  return (unsigned short)((u + 0x7fffu + ((u >> 16) & 1u)) >> 16);
}

__device__ __forceinline__ float dot8(float4 a0, float4 a1, float4 b0, float4 b1) {
  return a0.x*b0.x + a0.y*b0.y + a0.z*b0.z + a0.w*b0.w +
         a1.x*b1.x + a1.y*b1.y + a1.z*b1.z + a1.w*b1.w;
}

// s[b,c]: one wave per 4 outputs, lanes split d (coalesced 32B/lane).
__global__ __launch_bounds__(256) void k_mod(
    const float* __restrict__ style, const float* __restrict__ mw,
    const float* __restrict__ mb, float* __restrict__ s,
    float* __restrict__ zp) {
  if (blockIdx.x == 0) {                    // 4KB zero page
    zp[threadIdx.x] = 0.f; zp[256 + threadIdx.x] = 0.f;
    zp[512 + threadIdx.x] = 0.f; zp[768 + threadIdx.x] = 0.f;
  }
  int wv = blockIdx.x * 4 + (threadIdx.x >> 6);   // 0..1023
  int lane = threadIdx.x & 63;
  int t0 = wv * 4;
#pragma unroll
  for (int j = 0; j < 4; ++j) {
    int t = t0 + j, b = t >> 9, c = t & 511;
    const float4* mp = (const float4*)(mw + (size_t)c * 512 + lane * 8);
    const float4* sp = (const float4*)(style + (size_t)b * 512 + lane * 8);
    float p = dot8(mp[0], mp[1], sp[0], sp[1]);
#pragma unroll
    for (int off = 32; off; off >>= 1) p += __shfl_xor(p, off);
    if (lane == 0) s[t] = p * 0.04419417382415922f + mb[c];
  }
}

// wbf2[tap][c16(32)][o(512)][16c] bf16 + wsq[o][c]; per thread 2 c's.
__global__ __launch_bounds__(256) void k_wprep(
    const float* __restrict__ w, float* __restrict__ wsq,
    unsigned short* __restrict__ wbf2) {
  __shared__ float wl[4608];
  int o = blockIdx.x;              // 512
  int t = threadIdx.x;             // 256
  const float* wp = w + (size_t)o * 4608;
  for (int i = t; i < 4608; i += 256) wl[i] = wp[i];
  __syncthreads();
  int c0 = t * 2;
  float q0 = 0.f, q1 = 0.f;
  unsigned int rr[9];
#pragma unroll
  for (int k = 0; k < 9; ++k) {
    float v0 = wl[c0 * 9 + k], v1 = wl[c0 * 9 + 9 + k];
    q0 += v0 * v0; q1 += v1 * v1;
    rr[k] = (unsigned int)f2bf(v0) | ((unsigned int)f2bf(v1) << 16);
  }
  *(float2*)&wsq[o * 512 + c0] = make_float2(q0, q1);
#pragma unroll
  for (int k = 0; k < 9; ++k) {
    size_t idx = ((size_t)(k * 32 + (c0 >> 4)) * 512 + o) * 16 +
                 ((c0 >> 3) & 1) * 8 + (c0 & 7);
    *(unsigned int*)&wbf2[idx] = rr[k];
  }
}

// scale[b,o]: one wave per o; wsq row read once (coalesced), 8 dots vs s^2.
__global__ __launch_bounds__(256) void k_scale(
    const float* __restrict__ wsq, const float* __restrict__ s,
    float* __restrict__ scale) {
  int o = blockIdx.x * 4 + (threadIdx.x >> 6);    // 128 blocks
  int lane = threadIdx.x & 63;
  const float4* wp = (const float4*)(wsq + (size_t)o * 512 + lane * 8);
  float4 w0 = wp[0], w1 = wp[1];
  const float cs = 0.014731391274719739f;   // 1/sqrt(4608)
#pragma unroll
  for (int b = 0; b < 8; ++b) {
    const float4* sp = (const float4*)(s + (size_t)b * 512 + lane * 8);
    float4 s0 = sp[0], s1 = sp[1];
    s0.x *= s0.x; s0.y *= s0.y; s0.z *= s0.z; s0.w *= s0.w;
    s1.x *= s1.x; s1.y *= s1.y; s1.z *= s1.z; s1.w *= s1.w;
    float p = dot8(w0, w1, s0, s1);
#pragma unroll
    for (int off = 32; off; off >>= 1) p += __shfl_xor(p, off);
    if (lane == 0) scale[b * 512 + o] = cs * rsqrtf(cs * cs * p + 1e-8f);
  }
}

// xt[b][y][x][c] = bf16(s[b,c] * x[b,c,y,x]).
__global__ void k_xt(const float* __restrict__ x, const float* __restrict__ s,
                     unsigned short* __restrict__ xt) {
  __shared__ __align__(16) unsigned short tile[64 * 65 * 8];  // 66560 B
  int bid = blockIdx.x;            // 512 = b(8) * y(64)
  int b = bid >> 6, y = bid & 63;
  int t = threadIdx.x;             // 512
  int co = t >> 3, xo = t & 7;
  const float* xbase = x + ((size_t)(b * 512 + co * 8) * 64 + y) * 64 + xo * 8;
  float4 v[8][2];
#pragma unroll
  for (int j = 0; j < 8; ++j) {
    v[j][0] = *(const float4*)(xbase + (size_t)j * 4096);
    v[j][1] = *(const float4*)(xbase + (size_t)j * 4096 + 4);
  }
  float sv[8];
#pragma unroll
  for (int j = 0; j < 8; ++j) sv[j] = s[b * 512 + co * 8 + j];
#pragma unroll
  for (int k = 0; k < 8; ++k) {
    unsigned short r[8];
#pragma unroll
    for (int j = 0; j < 8; ++j) {
      float f = (k < 4) ? ((const float*)&v[j][0])[k & 3]
                        : ((const float*)&v[j][1])[k & 3];
      r[j] = f2bf(f * sv[j]);
    }
    int xr = xo * 8 + k;
    int unit = xr * 65 + (co ^ xr);
    *(ulonglong2*)&tile[unit * 8] = *(ulonglong2*)r;
  }
  __syncthreads();
  unsigned short* obase = xt + ((size_t)(b * 64 + y) * 64) * 512;
#pragma unroll
  for (int i = 0; i < 8; ++i) {
    int unit_o = i * 512 + t;
    int xr = unit_o >> 6, cor = unit_o & 63;
    int unit = xr * 65 + (cor ^ xr);
    *(ulonglong2*)&obase[(size_t)unit_o * 8] = *(const ulonglong2*)&tile[unit * 8];
  }
}

// ---------------- k_conv v11 ----------------
// Block = 128o x 16y x 32x, 8 waves: wid = wyy(0..3)*2 + wo(0..1).
// Wave = 64o x (4y x 32x), acc = 8 f32x16 frags.
// X LDS buffer (40KB = 40 issues x 1024B), entry = 16B = 8 c-values:
//   e = chunk(0..3)*612 + row(0..17)*34 + xi(0..33)
//   holds xt[yg*16+row-1][xg*32+xi-1][cc32*32 + chunk*8 ..+7] (zp if OOB)
// W: direct global->reg from wbf2[tap][c16][o][16c]; A-frag = coalesced
// 2KB gather; ping-pong S0/S1, 6 MFK clusters per phase (3kx x 2 subchunks).
#define BUFU  20480      // ushorts per buffer (40960 B)

__global__ __launch_bounds__(512, 2) void k_conv(
    const unsigned short* __restrict__ xt, const unsigned short* __restrict__ wbf2,
    const float* __restrict__ scale, const float* __restrict__ zp,
    float* __restrict__ out) {
  __shared__ __align__(16) unsigned short lds[2 * BUFU];  // 81920 B

  int bid = blockIdx.x;            // 256 = 8 b * 4 ob * 4 yg * 2 xg
  int b = bid & 7;                 // XCD k owns batch b=k
  int rest = bid >> 3;
  int ob = rest & 3;
  int rest2 = rest >> 2;
  int yg = rest2 & 3;
  int xg = rest2 >> 2;

  int tid = threadIdx.x;
  int wid = tid >> 6;              // 0..7
  int wo = wid & 1, wyy = wid >> 1;
  int lane = tid & 63, ln31 = lane & 31, hi = lane >> 5;

  // ---- X staging source pointers (5 issues per thread), +64B/phase ----
  const char* srcp[5];
  const char* xglob = (const char*)(xt + (size_t)b * 64 * 64 * 512);
#pragma unroll
  for (int i = 0; i < 5; ++i) {
    int is = wid + i * 8;          // 0..39
    int e = is * 64 + lane;
    int chunk = e / 612;
    int rem = e - chunk * 612;
    int row = rem / 34;
    int xi = rem - row * 34;
    int y = yg * 16 + row - 1, x = xg * 32 + xi - 1;
    bool ok = (chunk < 4) && (y >= 0) && (y < 64) && (x >= 0) && (x < 64);
    srcp[i] = ok ? xglob + 2 * ((y * 64 + x) * 512 + chunk * 8)
                 : (const char*)zp;
  }

  // ---- A (weight) lane base pointers: wbf2[tap][c16][o][16c] ----
  const char* aw0 = (const char*)wbf2 +
      2 * (((size_t)(ob * 128 + wo * 64 + ln31)) * 16 + hi * 8);
  const char* aw1 = aw0 + 1024;    // +32 o's

  f32x16 acc[8];   // [oh*4 + ry]
#pragma unroll
  for (int i = 0; i < 8; ++i)
    acc[i] = (f32x16){0,0,0,0,0,0,0,0,0,0,0,0,0,0,0,0};

  auto STAGE = [&](int bufu) {
#pragma unroll
    for (int i = 0; i < 5; ++i) {
      __builtin_amdgcn_global_load_lds(
          (const AS1 void*)srcp[i],
          (AS3 void*)&lds[bufu + (wid + i * 8) * 512], 16, 0, 0);
      srcp[i] += 64;
    }
  };

  // A-frags for one kx: 6 coalesced 2KB gathers (tap stride 512KB).
  auto LOADA = [&](int kx, int aoff, bf16x8* A) {
#pragma unroll
    for (int ky = 0; ky < 3; ++ky) {
      int tap = ky * 3 + kx;
      A[ky * 2]     = *(const bf16x8*)(aw0 + (size_t)tap * 524288 + aoff);
      A[ky * 2 + 1] = *(const bf16x8*)(aw1 + (size_t)tap * 524288 + aoff);
    }
  };

  // B-frags: sub s selects chunk pair {2s, 2s+1} (hi picks the 8-c half).
  auto LOADB = [&](const unsigned short* Xbp, int s, int kx, bf16x8* bv) {
#pragma unroll
    for (int rr = 0; rr < 6; ++rr)
      bv[rr] = *(const bf16x8*)&Xbp[s * 9792 + (rr * 34 + kx) * 8];
  };

  auto MFK = [&](const bf16x8* av, const bf16x8* bv) {
    __builtin_amdgcn_s_setprio(1);
#pragma unroll
    for (int ky = 0; ky < 3; ++ky) {
#pragma unroll
      for (int ry = 0; ry < 4; ++ry) {
        acc[ry] = __builtin_amdgcn_mfma_f32_32x32x16_bf16(
            av[ky * 2], bv[ry + ky], acc[ry], 0, 0, 0);
        acc[4 + ry] = __builtin_amdgcn_mfma_f32_32x32x16_bf16(
            av[ky * 2 + 1], bv[ry + ky], acc[4 + ry], 0, 0, 0);
      }
    }
    __builtin_amdgcn_s_setprio(0);
  };

  // read base (entry units *8 ushorts): chunk term (2s+hi)*612 -> hi folded in
  const unsigned short* Xw = &lds[(hi * 612 + wyy * 136 + ln31) * 8];

  bf16x8 S0[6], S1[6];

  STAGE(0);                         // phase 0 -> buf0
  LOADA(0, 0, S0);                  // A(kx0, sub0, phase 0)
  asm volatile("s_waitcnt vmcnt(6)" ::: "memory");   // 5 stage DMAs done
  __builtin_amdgcn_s_barrier();
  SB;

#pragma unroll 1
  for (int t = 0; t < 16; ++t) {
    const unsigned short* Xbp = Xw + (t & 1) * BUFU;
    int sbuf = ((t & 1) ^ 1) * BUFU;
    int aoff = t * 32768;
    bf16x8 bv[6];
    // --- sub0 ---
    LOADB(Xbp, 0, 0, bv);
    if (t < 15) STAGE(sbuf);
    LOADA(1, aoff, S1);
    MFK(S0, bv);
    LOADB(Xbp, 0, 1, bv);
    LOADA(2, aoff, S0);
    MFK(S1, bv);
    LOADB(Xbp, 0, 2, bv);
    LOADA(0, aoff + 16384, S1);
    MFK(S0, bv);
    // --- sub1 ---
    LOADB(Xbp, 1, 0, bv);
    LOADA(1, aoff + 16384, S0);
    MFK(S1, bv);
    LOADB(Xbp, 1, 1, bv);
    LOADA(2, aoff + 16384, S1);
    MFK(S0, bv);
    LOADB(Xbp, 1, 2, bv);
    if (t < 15) LOADA(0, aoff + 32768, S0);   // next phase kx0/sub0
    MFK(S1, bv);
    asm volatile("s_waitcnt vmcnt(36)" ::: "memory");  // stage DMAs retired
    __builtin_amdgcn_s_barrier();
    SB;
  }

  // ---- epilogue: C/D layout col=lane&31, row=(reg&3)+8*(reg>>2)+4*(lane>>5) ----
  const float* scp = scale + b * 512 + ob * 128 + wo * 64;
  float* op = out + (((size_t)(b * 512 + ob * 128 + wo * 64) * 64) +
                     yg * 16 + wyy * 4) * 64 + xg * 32 + ln31;
#pragma unroll
  for (int oh = 0; oh < 2; ++oh) {
#pragma unroll
    for (int ry = 0; ry < 4; ++ry) {
      const f32x16& A = acc[oh * 4 + ry];
#pragma unroll
      for (int reg = 0; reg < 16; ++reg) {
        int orow = (reg & 3) + 8 * (reg >> 2) + hi * 4;
        int ol = oh * 32 + orow;
        op[(size_t)ol * 4096 + ry * 64] = A[reg] * scp[ol];
      }
    }
  }
}

extern "C" void kernel_launch(void* const* d_in, const int* in_sizes, int n_in,
                              void* d_out, int out_size, void* d_ws, size_t ws_size,
                              hipStream_t stream) {
  const float* x     = (const float*)d_in[0];  // [8,512,64,64]
  const float* style = (const float*)d_in[1];  // [8,512]
  const float* w     = (const float*)d_in[2];  // [1,512,512,3,3]
  const float* mw    = (const float*)d_in[3];  // [512,512]
  const float* mb    = (const float*)d_in[4];  // [512]
  float* out = (float*)d_out;

  char* ws = (char*)d_ws;
  float* zp    = (float*)ws;                       // 4 KB zeros
  float* s     = (float*)(ws + 4096);              // 16 KB
  float* scale = (float*)(ws + 20480);             // 16 KB
  float* wsq   = (float*)(ws + 36864);             // 1 MB
  unsigned short* wbf2 = (unsigned short*)(ws + 1085440);  // 4.72 MB [9][32][512][16]
  unsigned short* xt   = (unsigned short*)(ws + 5804032);  // 33.5 MB [8][64][64][512]

  k_mod  <<<256,  256, 0, stream>>>(style, mw, mb, s, zp);
  k_wprep<<<512,  256, 0, stream>>>(w, wsq, wbf2);
  k_scale<<<128,  256, 0, stream>>>(wsq, s, scale);
  k_xt   <<<512,  512, 0, stream>>>(x, s, xt);
  k_conv <<<256,  512, 0, stream>>>(xt, wbf2, scale, zp, out);
}

// Round 12
// 174.888 us; speedup vs baseline: 1.3974x; 1.0037x over previous
//
#include <hip/hip_runtime.h>

// ModulatedConv2d (StyleGAN2): B=8, Cin=Cout=512, k=3, H=W=64.
//   s[b,c]     = style @ (mod_weight/sqrt(512))^T + bias          (fp32)
//   scale[b,o] = cs * rsqrt(cs^2 * sum_c wsq[o,c]*s^2 + eps)
//   out[b,o,p] = scale[b,o] * sum_{c,k} w[o,c,k] * (s[b,c]*x[b,c,p'])
// k_conv v12: TWO INDEPENDENT BLOCKS PER CU. Block = 4 waves (256 thr),
// wave = 64o x 4y x 32x; grid 512 = 2 blocks/CU; each SIMD hosts one wave
// from each block, so one block's barrier/load windows are filled by the
// other block's MFMA clusters. X-only quad-buffered LDS (4x12KB), STAGE
// issued at PHASE START for buf t+2 (A-use vmcnt only forces this phase's
// stage, hidden under kx0 MFMA); barrier-only phase boundary. W direct
// L2->reg ping-pong (v10/v11 path). BK=16, 32 phases.

typedef __bf16 bf16x8 __attribute__((ext_vector_type(8)));
typedef float f32x16 __attribute__((ext_vector_type(16)));

#define AS1 __attribute__((address_space(1)))
#define AS3 __attribute__((address_space(3)))
#define SB __builtin_amdgcn_sched_barrier(0)

__device__ __forceinline__ unsigned short f2bf(float f) {
  union { float f; unsigned int u; } v; v.f = f;
  unsigned int u = v.u;
  return (unsigned short)((u + 0x7fffu + ((u >> 16) & 1u)) >> 16);
}

__device__ __forceinline__ float dot8(float4 a0, float4 a1, float4 b0, float4 b1) {
  return a0.x*b0.x + a0.y*b0.y + a0.z*b0.z + a0.w*b0.w +
         a1.x*b1.x + a1.y*b1.y + a1.z*b1.z + a1.w*b1.w;
}

// s[b,c]: one wave per 4 outputs, lanes split d (coalesced 32B/lane).
__global__ __launch_bounds__(256) void k_mod(
    const float* __restrict__ style, const float* __restrict__ mw,
    const float* __restrict__ mb, float* __restrict__ s,
    float* __restrict__ zp) {
  if (blockIdx.x == 0) {                    // 4KB zero page
    zp[threadIdx.x] = 0.f; zp[256 + threadIdx.x] = 0.f;
    zp[512 + threadIdx.x] = 0.f; zp[768 + threadIdx.x] = 0.f;
  }
  int wv = blockIdx.x * 4 + (threadIdx.x >> 6);   // 0..1023
  int lane = threadIdx.x & 63;
  int t0 = wv * 4;
#pragma unroll
  for (int j = 0; j < 4; ++j) {
    int t = t0 + j, b = t >> 9, c = t & 511;
    const float4* mp = (const float4*)(mw + (size_t)c * 512 + lane * 8);
    const float4* sp = (const float4*)(style + (size_t)b * 512 + lane * 8);
    float p = dot8(mp[0], mp[1], sp[0], sp[1]);
#pragma unroll
    for (int off = 32; off; off >>= 1) p += __shfl_xor(p, off);
    if (lane == 0) s[t] = p * 0.04419417382415922f + mb[c];
  }
}

// wbf2[tap][c16(32)][o(512)][16c] bf16 + wsq[o][c]; per thread 2 c's.
__global__ __launch_bounds__(256) void k_wprep(
    const float* __restrict__ w, float* __restrict__ wsq,
    unsigned short* __restrict__ wbf2) {
  __shared__ float wl[4608];
  int o = blockIdx.x;              // 512
  int t = threadIdx.x;             // 256
  const float* wp = w + (size_t)o * 4608;
  for (int i = t; i < 4608; i += 256) wl[i] = wp[i];
  __syncthreads();
  int c0 = t * 2;
  float q0 = 0.f, q1 = 0.f;
  unsigned int rr[9];
#pragma unroll
  for (int k = 0; k < 9; ++k) {
    float v0 = wl[c0 * 9 + k], v1 = wl[c0 * 9 + 9 + k];
    q0 += v0 * v0; q1 += v1 * v1;
    rr[k] = (unsigned int)f2bf(v0) | ((unsigned int)f2bf(v1) << 16);
  }
  *(float2*)&wsq[o * 512 + c0] = make_float2(q0, q1);
#pragma unroll
  for (int k = 0; k < 9; ++k) {
    size_t idx = ((size_t)(k * 32 + (c0 >> 4)) * 512 + o) * 16 + (c0 & 15);
    *(unsigned int*)&wbf2[idx] = rr[k];
  }
}

// scale[b,o]: one wave per o; wsq row read once (coalesced), 8 dots vs s^2.
__global__ __launch_bounds__(256) void k_scale(
    const float* __restrict__ wsq, const float* __restrict__ s,
    float* __restrict__ scale) {
  int o = blockIdx.x * 4 + (threadIdx.x >> 6);    // 128 blocks
  int lane = threadIdx.x & 63;
  const float4* wp = (const float4*)(wsq + (size_t)o * 512 + lane * 8);
  float4 w0 = wp[0], w1 = wp[1];
  const float cs = 0.014731391274719739f;   // 1/sqrt(4608)
#pragma unroll
  for (int b = 0; b < 8; ++b) {
    const float4* sp = (const float4*)(s + (size_t)b * 512 + lane * 8);
    float4 s0 = sp[0], s1 = sp[1];
    s0.x *= s0.x; s0.y *= s0.y; s0.z *= s0.z; s0.w *= s0.w;
    s1.x *= s1.x; s1.y *= s1.y; s1.z *= s1.z; s1.w *= s1.w;
    float p = dot8(w0, w1, s0, s1);
#pragma unroll
    for (int off = 32; off; off >>= 1) p += __shfl_xor(p, off);
    if (lane == 0) scale[b * 512 + o] = cs * rsqrtf(cs * cs * p + 1e-8f);
  }
}

// xt[b][y][x][c] = bf16(s[b,c] * x[b,c,y,x]).
__global__ void k_xt(const float* __restrict__ x, const float* __restrict__ s,
                     unsigned short* __restrict__ xt) {
  __shared__ __align__(16) unsigned short tile[64 * 65 * 8];  // 66560 B
  int bid = blockIdx.x;            // 512 = b(8) * y(64)
  int b = bid >> 6, y = bid & 63;
  int t = threadIdx.x;             // 512
  int co = t >> 3, xo = t & 7;
  const float* xbase = x + ((size_t)(b * 512 + co * 8) * 64 + y) * 64 + xo * 8;
  float4 v[8][2];
#pragma unroll
  for (int j = 0; j < 8; ++j) {
    v[j][0] = *(const float4*)(xbase + (size_t)j * 4096);
    v[j][1] = *(const float4*)(xbase + (size_t)j * 4096 + 4);
  }
  float sv[8];
#pragma unroll
  for (int j = 0; j < 8; ++j) sv[j] = s[b * 512 + co * 8 + j];
#pragma unroll
  for (int k = 0; k < 8; ++k) {
    unsigned short r[8];
#pragma unroll
    for (int j = 0; j < 8; ++j) {
      float f = (k < 4) ? ((const float*)&v[j][0])[k & 3]
                        : ((const float*)&v[j][1])[k & 3];
      r[j] = f2bf(f * sv[j]);
    }
    int xr = xo * 8 + k;
    int unit = xr * 65 + (co ^ xr);
    *(ulonglong2*)&tile[unit * 8] = *(ulonglong2*)r;
  }
  __syncthreads();
  unsigned short* obase = xt + ((size_t)(b * 64 + y) * 64) * 512;
#pragma unroll
  for (int i = 0; i < 8; ++i) {
    int unit_o = i * 512 + t;
    int xr = unit_o >> 6, cor = unit_o & 63;
    int unit = xr * 65 + (cor ^ xr);
    *(ulonglong2*)&obase[(size_t)unit_o * 8] = *(const ulonglong2*)&tile[unit * 8];
  }
}

// ---------------- k_conv v12 ----------------
// Block = 128o x 8y x 32x, 4 waves: wid = wyy(0..1)*2 + wo(0..1).
// Wave = 64o x (4y x 32x), acc = 8 f32x16 frags.
// X LDS buffer (12 issues x 1024B = 12KB; 11 real + 1 pad), quad-buffered.
//   entry e = chunk(0..1)*340 + row(0..9)*34 + xi(0..33):
//   holds xt[yg*8+row-1][xg*32+xi-1][cc*16 + chunk*8 ..+7]  (zp if OOB/pad)
// W: direct global->reg from wbf2[tap][c16][o][16c]; A-frag = coalesced
// 2KB gather, ping-pong S0/S1 across kx clusters.
#define BUFU  6144       // ushorts per buffer (12288 B)

__global__ __launch_bounds__(256, 2) void k_conv(
    const unsigned short* __restrict__ xt, const unsigned short* __restrict__ wbf2,
    const float* __restrict__ scale, const float* __restrict__ zp,
    float* __restrict__ out) {
  __shared__ __align__(16) unsigned short lds[4 * BUFU];  // 49152 B

  int bid = blockIdx.x;            // 512 = 8 b * 4 ob * 8 yg * 2 xg
  int b = bid & 7;                 // XCD k owns batch b=k
  int rest = bid >> 3;
  int ob = rest & 3;
  int rest2 = rest >> 2;
  int yg = rest2 & 7;
  int xg = rest2 >> 3;

  int tid = threadIdx.x;
  int wid = tid >> 6;              // 0..3
  int wo = wid & 1, wyy = wid >> 1;
  int lane = tid & 63, ln31 = lane & 31, hi = lane >> 5;

  // ---- X staging source pointers (3 issues per thread), +32B/stage ----
  const char* srcp[3];
  const char* xglob = (const char*)(xt + (size_t)b * 64 * 64 * 512);
#pragma unroll
  for (int i = 0; i < 3; ++i) {
    int is = wid + i * 4;          // 0..11
    const char* p = (const char*)zp;
    if (is < 11) {
      int e = is * 64 + lane;
      int chunk = e / 340;
      int rem = e - chunk * 340;
      int row = rem / 34;
      int xi = rem - row * 34;
      int y = yg * 8 + row - 1, x = xg * 32 + xi - 1;
      bool ok = (chunk < 2) && (y >= 0) && (y < 64) && (x >= 0) && (x < 64);
      if (ok) p = xglob + 2 * ((y * 64 + x) * 512 + chunk * 8);
    }
    srcp[i] = p;
  }

  // ---- A (weight) lane base pointers: wbf2[tap][c16][o][16c] ----
  const char* aw0 = (const char*)wbf2 +
      2 * (((size_t)(ob * 128 + wo * 64 + ln31)) * 16 + hi * 8);
  const char* aw1 = aw0 + 1024;    // +32 o's

  f32x16 acc[8];   // [oh*4 + ry]
#pragma unroll
  for (int i = 0; i < 8; ++i)
    acc[i] = (f32x16){0,0,0,0,0,0,0,0,0,0,0,0,0,0,0,0};

  auto STAGE = [&](int bufu) {
#pragma unroll
    for (int i = 0; i < 3; ++i) {
      __builtin_amdgcn_global_load_lds(
          (const AS1 void*)srcp[i],
          (AS3 void*)&lds[bufu + (wid + i * 4) * 512], 16, 0, 0);
      srcp[i] += 32;
    }
  };

  // A-frags for one kx: 6 coalesced 2KB gathers (tap stride 512KB).
  auto LOADA = [&](int kx, int aoff, bf16x8* A) {
#pragma unroll
    for (int ky = 0; ky < 3; ++ky) {
      int tap = ky * 3 + kx;
      A[ky * 2]     = *(const bf16x8*)(aw0 + (size_t)tap * 524288 + aoff);
      A[ky * 2 + 1] = *(const bf16x8*)(aw1 + (size_t)tap * 524288 + aoff);
    }
  };

  auto LOADB = [&](const unsigned short* Xbp, int kx, bf16x8* bv) {
#pragma unroll
    for (int rr = 0; rr < 6; ++rr)
      bv[rr] = *(const bf16x8*)&Xbp[(rr * 34 + kx) * 8];
  };

  auto MFK = [&](const bf16x8* av, const bf16x8* bv) {
    __builtin_amdgcn_s_setprio(1);
#pragma unroll
    for (int ky = 0; ky < 3; ++ky) {
#pragma unroll
      for (int ry = 0; ry < 4; ++ry) {
        acc[ry] = __builtin_amdgcn_mfma_f32_32x32x16_bf16(
            av[ky * 2], bv[ry + ky], acc[ry], 0, 0, 0);
        acc[4 + ry] = __builtin_amdgcn_mfma_f32_32x32x16_bf16(
            av[ky * 2 + 1], bv[ry + ky], acc[4 + ry], 0, 0, 0);
      }
    }
    __builtin_amdgcn_s_setprio(0);
  };

  const unsigned short* Xw = &lds[(hi * 340 + wyy * 136 + ln31) * 8];

  bf16x8 S0[6], S1[6];

  // Prologue: stage cc0->buf0, cc1->buf1; A(kx0, cc0); wait buf0 only.
  STAGE(0);
  STAGE(BUFU);
  LOADA(0, 0, S0);
  asm volatile("s_waitcnt vmcnt(18)" ::: "memory");   // buf0's 3 DMAs retired
  __builtin_amdgcn_s_barrier();
  SB;

  // One phase: STAGE(t+2) FIRST (A-use waits then only force this stage,
  // which lands under kx0's MFMA), then 3 kx clusters with A ping-pong.
  auto PHASE = [&](int t, bf16x8* Su, bf16x8* Sl) {
    const unsigned short* Xbp = Xw + (t & 3) * BUFU;
    int aoff = t * 16384;
    bf16x8 bv[6];
    if (t < 30) STAGE(((t + 2) & 3) * BUFU);
    LOADB(Xbp, 0, bv);
    LOADA(1, aoff, Sl);
    MFK(Su, bv);
    LOADB(Xbp, 1, bv);
    LOADA(2, aoff, Su);
    MFK(Sl, bv);
    LOADB(Xbp, 2, bv);
    if (t < 31) LOADA(0, aoff + 16384, Sl);
    MFK(Su, bv);
    __builtin_amdgcn_s_barrier();
    SB;
  };

#pragma unroll 1
  for (int t = 0; t < 32; t += 2) {
    PHASE(t, S0, S1);
    PHASE(t + 1, S1, S0);
  }

  // ---- epilogue: C/D layout col=lane&31, row=(reg&3)+8*(reg>>2)+4*(lane>>5) ----
  const float* scp = scale + b * 512 + ob * 128 + wo * 64;
  float* op = out + (((size_t)(b * 512 + ob * 128 + wo * 64) * 64) +
                     yg * 8 + wyy * 4) * 64 + xg * 32 + ln31;
#pragma unroll
  for (int oh = 0; oh < 2; ++oh) {
#pragma unroll
    for (int ry = 0; ry < 4; ++ry) {
      const f32x16& A = acc[oh * 4 + ry];
#pragma unroll
      for (int reg = 0; reg < 16; ++reg) {
        int orow = (reg & 3) + 8 * (reg >> 2) + hi * 4;
        int ol = oh * 32 + orow;
        op[(size_t)ol * 4096 + ry * 64] = A[reg] * scp[ol];
      }
    }
  }
}

extern "C" void kernel_launch(void* const* d_in, const int* in_sizes, int n_in,
                              void* d_out, int out_size, void* d_ws, size_t ws_size,
                              hipStream_t stream) {
  const float* x     = (const float*)d_in[0];  // [8,512,64,64]
  const float* style = (const float*)d_in[1];  // [8,512]
  const float* w     = (const float*)d_in[2];  // [1,512,512,3,3]
  const float* mw    = (const float*)d_in[3];  // [512,512]
  const float* mb    = (const float*)d_in[4];  // [512]
  float* out = (float*)d_out;

  char* ws = (char*)d_ws;
  float* zp    = (float*)ws;                       // 4 KB zeros
  float* s     = (float*)(ws + 4096);              // 16 KB
  float* scale = (float*)(ws + 20480);             // 16 KB
  float* wsq   = (float*)(ws + 36864);             // 1 MB
  unsigned short* wbf2 = (unsigned short*)(ws + 1085440);  // 4.72 MB [9][32][512][16]
  unsigned short* xt   = (unsigned short*)(ws + 5804032);  // 33.5 MB [8][64][64][512]

  k_mod  <<<256,  256, 0, stream>>>(style, mw, mb, s, zp);
  k_wprep<<<512,  256, 0, stream>>>(w, wsq, wbf2);
  k_scale<<<128,  256, 0, stream>>>(wsq, s, scale);
  k_xt   <<<512,  512, 0, stream>>>(x, s, xt);
  k_conv <<<512,  256, 0, stream>>>(xt, wbf2, scale, zp, out);
}